// Round 1
// baseline (904.748 us; speedup 1.0000x reference)
//
#include <hip/hip_runtime.h>
#include <math.h>

// ---------------------------------------------------------------------------
// MS-SSIM 3D (window 11, sigma 1.5, 5 levels) for (2,1,192,192,192) fp32 pairs.
//
// ws float layout:
//   [0..4]   ssim_sum[level]      (float atomics)
//   [5..9]   cs_sum[level]        (float atomics)
//   [10..14] min_enc[level]       (sortable-uint atomicMin)
//   [15..19] max_enc[level]       (sortable-uint atomicMax)
//   [32.. ]  pyramid images (levels 1..4, img1 then img2 per level)
// ---------------------------------------------------------------------------

__device__ __forceinline__ unsigned enc_f(float f) {
    unsigned u = __float_as_uint(f);
    return (u & 0x80000000u) ? ~u : (u | 0x80000000u);
}
__device__ __forceinline__ float dec_f(unsigned e) {
    unsigned u = (e & 0x80000000u) ? (e ^ 0x80000000u) : ~e;
    return __uint_as_float(u);
}

__global__ void init_kernel(float* wsf) {
    unsigned* wsu = (unsigned*)wsf;
    int t = threadIdx.x;
    if (t < 10)       wsf[t] = 0.0f;
    else if (t < 15)  wsu[t] = 0xFFFFFFFFu;  // min slots
    else if (t < 20)  wsu[t] = 0u;           // max slots
}

__global__ void minmax_kernel(const float4* __restrict__ in, long n4,
                              unsigned* wsu, int lvl) {
    float mn = INFINITY, mx = -INFINITY;
    long stride = (long)gridDim.x * blockDim.x;
    for (long i = (long)blockIdx.x * blockDim.x + threadIdx.x; i < n4; i += stride) {
        float4 v = in[i];
        mn = fminf(mn, fminf(fminf(v.x, v.y), fminf(v.z, v.w)));
        mx = fmaxf(mx, fmaxf(fmaxf(v.x, v.y), fmaxf(v.z, v.w)));
    }
    for (int o = 32; o; o >>= 1) {
        mn = fminf(mn, __shfl_down(mn, o));
        mx = fmaxf(mx, __shfl_down(mx, o));
    }
    __shared__ float smn[4], smx[4];
    int lane = threadIdx.x & 63, w = threadIdx.x >> 6;
    if (lane == 0) { smn[w] = mn; smx[w] = mx; }
    __syncthreads();
    if (threadIdx.x == 0) {
        for (int i = 1; i < 4; i++) { mn = fminf(mn, smn[i]); mx = fmaxf(mx, smx[i]); }
        atomicMin(&wsu[10 + lvl], enc_f(mn));
        atomicMax(&wsu[15 + lvl], enc_f(mx));
    }
}

// 2x2x2 avg pool of both images; fused min/max of pooled img1 -> slot lvl_next.
__global__ void pool_kernel(const float* __restrict__ i1, const float* __restrict__ i2,
                            float* __restrict__ o1, float* __restrict__ o2,
                            int D, int Dh, int n, unsigned* wsu, int lvl_next) {
    int idx = blockIdx.x * blockDim.x + threadIdx.x;
    float vmn = INFINITY, vmx = -INFINITY;
    if (idx < n) {
        int Dh2 = Dh * Dh;
        int Dh3 = Dh2 * Dh;
        int b = idx / Dh3; int r = idx - b * Dh3;
        int z = r / Dh2;   r -= z * Dh2;
        int y = r / Dh;    int x = r - y * Dh;
        long base = (long)b * D * D * D + (long)(2 * z) * D * D + (long)(2 * y) * D + 2 * x;
        float2 a00 = *(const float2*)(i1 + base);
        float2 a01 = *(const float2*)(i1 + base + D);
        float2 a10 = *(const float2*)(i1 + base + (long)D * D);
        float2 a11 = *(const float2*)(i1 + base + (long)D * D + D);
        float s1 = (a00.x + a00.y + a01.x + a01.y + a10.x + a10.y + a11.x + a11.y) * 0.125f;
        float2 b00 = *(const float2*)(i2 + base);
        float2 b01 = *(const float2*)(i2 + base + D);
        float2 b10 = *(const float2*)(i2 + base + (long)D * D);
        float2 b11 = *(const float2*)(i2 + base + (long)D * D + D);
        float s2 = (b00.x + b00.y + b01.x + b01.y + b10.x + b10.y + b11.x + b11.y) * 0.125f;
        o1[idx] = s1;
        o2[idx] = s2;
        vmn = s1; vmx = s1;
    }
    for (int o = 32; o; o >>= 1) {
        vmn = fminf(vmn, __shfl_down(vmn, o));
        vmx = fmaxf(vmx, __shfl_down(vmx, o));
    }
    __shared__ float smn[4], smx[4];
    int lane = threadIdx.x & 63, w = threadIdx.x >> 6;
    if (lane == 0) { smn[w] = vmn; smx[w] = vmx; }
    __syncthreads();
    if (threadIdx.x == 0) {
        for (int i = 1; i < 4; i++) { vmn = fminf(vmn, smn[i]); vmx = fmaxf(vmx, smx[i]); }
        atomicMin(&wsu[10 + lvl_next], enc_f(vmn));
        atomicMax(&wsu[15 + lvl_next], enc_f(vmx));
    }
}

// ---------------------------------------------------------------------------
// Fused SSIM kernel: per block a 16(x) x 32(y) output tile swept over a z-chunk.
// Per z input plane: stage (a,b) ext tile in LDS -> x-conv of 5 fields into LDS
// -> y-conv per thread (2 owned rows) -> z-conv via register ring (11 deep).
// ---------------------------------------------------------------------------
#define TSX 16
#define TSY 32
#define EXR (TSY + 10)   // 42 ext rows
#define EXC (TSX + 10)   // 26 ext cols
#define TXP 20           // padded col stride for x-conv output (float4 aligned)
#define NPIX (EXR * EXC) // 1092

__launch_bounds__(256, 2)
__global__ void ssim_kernel(const float* __restrict__ img1, const float* __restrict__ img2,
                            int D, int O, int ZC, float* wsf, int level) {
    __shared__ float2 S[EXR][EXC];
    __shared__ float  TX[5][EXR][TXP];
    __shared__ float2 RED[256];

    const int tid = threadIdx.x;
    const int col = tid & 15;
    const int ty  = tid >> 4;

    // Gaussian taps (matches np float32: exp(-(i-5)^2/4.5) / sum)
    float g[11];
    {
        float s = 0.f;
#pragma unroll
        for (int i = 0; i < 11; i++) {
            float d = (float)(i - 5);
            g[i] = expf(-d * d / 4.5f);
            s += g[i];
        }
#pragma unroll
        for (int i = 0; i < 11; i++) g[i] /= s;
    }

    // C1/C2 from this level's img1 min/max (computed by preceding kernel)
    const unsigned* wsu = (const unsigned*)wsf;
    float mxv = dec_f(wsu[15 + level]);
    float mnv = dec_f(wsu[10 + level]);
    float maxval = (mxv > 128.f) ? 255.f : 1.f;
    float minval = (mnv < -0.5f) ? -1.f : 0.f;
    float Lr = maxval - minval;
    float C1 = 0.01f * Lr; C1 *= C1;
    float C2 = 0.03f * Lr; C2 *= C2;

    const int ZCn   = (O + ZC - 1) / ZC;
    const int batch = blockIdx.z / ZCn;
    const int oz0   = (blockIdx.z - batch * ZCn) * ZC;
    const int oz1   = min(oz0 + ZC, O);
    const int ox0   = blockIdx.x * TSX;
    const int oy0   = blockIdx.y * TSY;
    const int D2    = D * D;
    const float* A  = img1 + (long)batch * D * D2;
    const float* B  = img2 + (long)batch * D * D2;

    // per-thread staging slots (plane-invariant offsets)
    int  poff[5];
    bool pval[5];
#pragma unroll
    for (int k = 0; k < 5; k++) {
        int idx = tid + (k << 8);
        pval[k] = (idx < NPIX);
        int row = idx / EXC;
        int c   = idx - row * EXC;
        int gy = min(oy0 + row, D - 1);
        int gx = min(ox0 + c,   D - 1);
        poff[k] = gy * D + gx;
    }

    float ring[5][2][11] = {};
    float ssim_acc = 0.f, cs_acc = 0.f;

    const int  oyA = oy0 + 2 * ty;
    const int  ox  = ox0 + col;
    const bool vx  = (ox < O);
    const bool vyA = vx && (oyA < O);
    const bool vyB = vx && (oyA + 1 < O);

    // preload first plane
    float2 P[5];
    {
        long zoff = (long)oz0 * D2;
#pragma unroll
        for (int k = 0; k < 5; k++)
            if (pval[k]) P[k] = make_float2(A[zoff + poff[k]], B[zoff + poff[k]]);
    }

    for (int zp = oz0; zp < oz1 + 10; ++zp) {
        __syncthreads();  // prev x-conv (S readers) done
#pragma unroll
        for (int k = 0; k < 5; k++) {
            int idx = tid + (k << 8);
            if (idx < NPIX) ((float2*)S)[idx] = P[k];
        }
        // prefetch next plane while this one is processed
        if (zp + 1 < oz1 + 10) {
            long zoff = (long)(zp + 1) * D2;
#pragma unroll
            for (int k = 0; k < 5; k++)
                if (pval[k]) P[k] = make_float2(A[zoff + poff[k]], B[zoff + poff[k]]);
        }
        __syncthreads();

        // ---- x-conv: 168 tasks, each a run of 4 output cols in one ext row
        if (tid < EXR * 4) {
            int row = tid >> 2;
            int c0  = (tid & 3) << 2;
            float2 p[14];
#pragma unroll
            for (int i = 0; i < 14; i++) p[i] = S[row][c0 + i];
            float acc[4][5];
#pragma unroll
            for (int c = 0; c < 4; c++)
#pragma unroll
                for (int f = 0; f < 5; f++) acc[c][f] = 0.f;
#pragma unroll
            for (int i = 0; i < 11; i++) {
                float w = g[i];
#pragma unroll
                for (int c = 0; c < 4; c++) {
                    float a = p[i + c].x, b = p[i + c].y;
                    float wa = w * a, wb = w * b;
                    acc[c][0] += wa;
                    acc[c][1] += wb;
                    acc[c][2] += wa * a;
                    acc[c][3] += wb * b;
                    acc[c][4] += wa * b;
                }
            }
#pragma unroll
            for (int f = 0; f < 5; f++) {
                float4 v = make_float4(acc[0][f], acc[1][f], acc[2][f], acc[3][f]);
                *(float4*)&TX[f][row][c0] = v;
            }
        }
        __syncthreads();

        // ---- y-conv (2 owned rows share reads) + z ring push
#pragma unroll
        for (int f = 0; f < 5; f++) {
            float t[12];
#pragma unroll
            for (int j = 0; j < 12; j++) t[j] = TX[f][2 * ty + j][col];
            float s0 = 0.f, s1 = 0.f;
#pragma unroll
            for (int j = 0; j < 11; j++) { s0 += g[j] * t[j]; s1 += g[j] * t[j + 1]; }
#pragma unroll
            for (int k = 0; k < 10; k++) {
                ring[f][0][k] = ring[f][0][k + 1];
                ring[f][1][k] = ring[f][1][k + 1];
            }
            ring[f][0][10] = s0;
            ring[f][1][10] = s1;
        }

        // ---- completed output plane
        if (zp >= oz0 + 10) {
#pragma unroll
            for (int y2 = 0; y2 < 2; y2++) {
                bool valid = y2 ? vyB : vyA;
                if (!valid) continue;
                float m1 = 0.f, m2 = 0.f, s11 = 0.f, s22 = 0.f, s12 = 0.f;
#pragma unroll
                for (int k = 0; k < 11; k++) {
                    float w = g[k];
                    m1  += w * ring[0][y2][k];
                    m2  += w * ring[1][y2][k];
                    s11 += w * ring[2][y2][k];
                    s22 += w * ring[3][y2][k];
                    s12 += w * ring[4][y2][k];
                }
                float mu11 = m1 * m1, mu22 = m2 * m2, mu12 = m1 * m2;
                float sg1 = s11 - mu11, sg2 = s22 - mu22, sg12 = s12 - mu12;
                float v1 = 2.f * sg12 + C2;
                float v2 = sg1 + sg2 + C2;
                float csv = v1 / v2;
                float ssimv = ((2.f * mu12 + C1) * v1) / ((mu11 + mu22 + C1) * v2);
                cs_acc += csv;
                ssim_acc += ssimv;
            }
        }
    }

    // block reduce + one atomic pair
    RED[tid] = make_float2(ssim_acc, cs_acc);
    __syncthreads();
    for (int s = 128; s > 0; s >>= 1) {
        if (tid < s) {
            RED[tid].x += RED[tid + s].x;
            RED[tid].y += RED[tid + s].y;
        }
        __syncthreads();
    }
    if (tid == 0) {
        atomicAdd(&wsf[level],     RED[0].x);
        atomicAdd(&wsf[5 + level], RED[0].y);
    }
}

__global__ void final_kernel(const float* wsf, float* out,
                             double c0, double c1, double c2, double c3, double c4) {
    if (threadIdx.x != 0 || blockIdx.x != 0) return;
    double cnt[5] = {c0, c1, c2, c3, c4};
    double w[5];
    w[0] = (double)0.0448f; w[1] = (double)0.2856f; w[2] = (double)0.3001f;
    w[3] = (double)0.2363f; w[4] = (double)0.1333f;
    double prod = 1.0;
    for (int l = 0; l < 4; l++) {
        double cs = (double)wsf[5 + l] / cnt[l];
        prod *= pow(cs, w[l]);
    }
    double sm = (double)wsf[4] / cnt[4];
    prod *= pow(sm, w[4]);
    out[0] = (float)prod;
}

extern "C" void kernel_launch(void* const* d_in, const int* in_sizes, int n_in,
                              void* d_out, int out_size, void* d_ws, size_t ws_size,
                              hipStream_t stream) {
    (void)in_sizes; (void)n_in; (void)out_size; (void)ws_size;
    const float* img1 = (const float*)d_in[0];
    const float* img2 = (const float*)d_in[1];
    float*    wsf = (float*)d_ws;
    unsigned* wsu = (unsigned*)d_ws;
    float*    out = (float*)d_out;

    const int Ds[5]  = {192, 96, 48, 24, 12};
    const int ZCs[5] = {26, 15, 10, 7, 2};

    // pyramid buffers in workspace
    float* bufA[5] = {nullptr};
    float* bufB[5] = {nullptr};
    size_t o = 32;
    for (int l = 1; l < 5; l++) {
        long n = 2L * Ds[l] * Ds[l] * Ds[l];
        bufA[l] = wsf + o; o += (size_t)n;
        bufB[l] = wsf + o; o += (size_t)n;
    }

    init_kernel<<<1, 64, 0, stream>>>(wsf);

    long n0 = 2L * 192 * 192 * 192;
    minmax_kernel<<<2048, 256, 0, stream>>>((const float4*)img1, n0 / 4, wsu, 0);

    const float* pA = img1;
    const float* pB = img2;
    for (int l = 0; l < 5; l++) {
        int D = Ds[l], O = D - 10, ZC = ZCs[l];
        int ZCn = (O + ZC - 1) / ZC;
        dim3 grid((O + TSX - 1) / TSX, (O + TSY - 1) / TSY, 2 * ZCn);
        ssim_kernel<<<grid, dim3(256), 0, stream>>>(pA, pB, D, O, ZC, wsf, l);
        if (l < 4) {
            int Dh = Ds[l + 1];
            long n = 2L * Dh * Dh * Dh;
            pool_kernel<<<(int)((n + 255) / 256), 256, 0, stream>>>(
                pA, pB, bufA[l + 1], bufB[l + 1], D, Dh, (int)n, wsu, l + 1);
            pA = bufA[l + 1];
            pB = bufB[l + 1];
        }
    }

    double cnts[5];
    for (int l = 0; l < 5; l++) {
        double Od = (double)(Ds[l] - 10);
        cnts[l] = 2.0 * Od * Od * Od;
    }
    final_kernel<<<1, 64, 0, stream>>>(wsf, out, cnts[0], cnts[1], cnts[2], cnts[3], cnts[4]);
}

// Round 2
// 622.040 us; speedup vs baseline: 1.4545x; 1.4545x over previous
//
#include <hip/hip_runtime.h>
#include <math.h>

// ---------------------------------------------------------------------------
// MS-SSIM 3D (window 11, sigma 1.5, 5 levels) for (2,1,192,192,192) fp32 pairs.
//
// ws float layout:
//   [0..4]   ssim_sum[level]      (float atomics)
//   [5..9]   cs_sum[level]        (float atomics)
//   [10..14] min_enc[level]       (sortable-uint atomicMin)
//   [15..19] max_enc[level]       (sortable-uint atomicMax)
//   [32.. ]  pyramid images (levels 1..4, img1 then img2 per level)
//
// R2: 16x16 output tile, 1 output column per thread (ring[5][11]=55 regs, no
// spill), x-conv output packed float4+float for vector LDS y-reads.
// ---------------------------------------------------------------------------

__device__ __forceinline__ unsigned enc_f(float f) {
    unsigned u = __float_as_uint(f);
    return (u & 0x80000000u) ? ~u : (u | 0x80000000u);
}
__device__ __forceinline__ float dec_f(unsigned e) {
    unsigned u = (e & 0x80000000u) ? (e ^ 0x80000000u) : ~e;
    return __uint_as_float(u);
}

__global__ void init_kernel(float* wsf) {
    unsigned* wsu = (unsigned*)wsf;
    int t = threadIdx.x;
    if (t < 10)       wsf[t] = 0.0f;
    else if (t < 15)  wsu[t] = 0xFFFFFFFFu;  // min slots
    else if (t < 20)  wsu[t] = 0u;           // max slots
}

__global__ void minmax_kernel(const float4* __restrict__ in, long n4,
                              unsigned* wsu, int lvl) {
    float mn = INFINITY, mx = -INFINITY;
    long stride = (long)gridDim.x * blockDim.x;
    for (long i = (long)blockIdx.x * blockDim.x + threadIdx.x; i < n4; i += stride) {
        float4 v = in[i];
        mn = fminf(mn, fminf(fminf(v.x, v.y), fminf(v.z, v.w)));
        mx = fmaxf(mx, fmaxf(fmaxf(v.x, v.y), fmaxf(v.z, v.w)));
    }
    for (int o = 32; o; o >>= 1) {
        mn = fminf(mn, __shfl_down(mn, o));
        mx = fmaxf(mx, __shfl_down(mx, o));
    }
    __shared__ float smn[4], smx[4];
    int lane = threadIdx.x & 63, w = threadIdx.x >> 6;
    if (lane == 0) { smn[w] = mn; smx[w] = mx; }
    __syncthreads();
    if (threadIdx.x == 0) {
        for (int i = 1; i < 4; i++) { mn = fminf(mn, smn[i]); mx = fmaxf(mx, smx[i]); }
        atomicMin(&wsu[10 + lvl], enc_f(mn));
        atomicMax(&wsu[15 + lvl], enc_f(mx));
    }
}

// 2x2x2 avg pool of both images; fused min/max of pooled img1 -> slot lvl_next.
__global__ void pool_kernel(const float* __restrict__ i1, const float* __restrict__ i2,
                            float* __restrict__ o1, float* __restrict__ o2,
                            int D, int Dh, int n, unsigned* wsu, int lvl_next) {
    int idx = blockIdx.x * blockDim.x + threadIdx.x;
    float vmn = INFINITY, vmx = -INFINITY;
    if (idx < n) {
        int Dh2 = Dh * Dh;
        int Dh3 = Dh2 * Dh;
        int b = idx / Dh3; int r = idx - b * Dh3;
        int z = r / Dh2;   r -= z * Dh2;
        int y = r / Dh;    int x = r - y * Dh;
        long base = (long)b * D * D * D + (long)(2 * z) * D * D + (long)(2 * y) * D + 2 * x;
        float2 a00 = *(const float2*)(i1 + base);
        float2 a01 = *(const float2*)(i1 + base + D);
        float2 a10 = *(const float2*)(i1 + base + (long)D * D);
        float2 a11 = *(const float2*)(i1 + base + (long)D * D + D);
        float s1 = (a00.x + a00.y + a01.x + a01.y + a10.x + a10.y + a11.x + a11.y) * 0.125f;
        float2 b00 = *(const float2*)(i2 + base);
        float2 b01 = *(const float2*)(i2 + base + D);
        float2 b10 = *(const float2*)(i2 + base + (long)D * D);
        float2 b11 = *(const float2*)(i2 + base + (long)D * D + D);
        float s2 = (b00.x + b00.y + b01.x + b01.y + b10.x + b10.y + b11.x + b11.y) * 0.125f;
        o1[idx] = s1;
        o2[idx] = s2;
        vmn = s1; vmx = s1;
    }
    for (int o = 32; o; o >>= 1) {
        vmn = fminf(vmn, __shfl_down(vmn, o));
        vmx = fmaxf(vmx, __shfl_down(vmx, o));
    }
    __shared__ float smn[4], smx[4];
    int lane = threadIdx.x & 63, w = threadIdx.x >> 6;
    if (lane == 0) { smn[w] = vmn; smx[w] = vmx; }
    __syncthreads();
    if (threadIdx.x == 0) {
        for (int i = 1; i < 4; i++) { vmn = fminf(vmn, smn[i]); vmx = fmaxf(vmx, smx[i]); }
        atomicMin(&wsu[10 + lvl_next], enc_f(vmn));
        atomicMax(&wsu[15 + lvl_next], enc_f(vmx));
    }
}

// ---------------------------------------------------------------------------
// Fused SSIM kernel: 16x16 output tile per block, swept over a z-chunk.
// Per input plane: stage (a,b) ext tile (26x26 float2) in LDS -> x-conv of 5
// fields (packed float4 + float) -> y-conv per thread -> z-conv via 55-reg ring.
// ---------------------------------------------------------------------------
#define TSX 16
#define TSY 16
#define EXN 26            // ext rows/cols (16+10)
#define SPS 28            // S row stride in float2 (16B aligned rows)
#define TPS 17            // TX row stride in elements

__launch_bounds__(256, 3)
__global__ void ssim_kernel(const float* __restrict__ img1, const float* __restrict__ img2,
                            int D, int O, int ZC, float* wsf, int level) {
    __shared__ __align__(16) float2 S[EXN * SPS];
    __shared__ __align__(16) float4 TX4[EXN * TPS];
    __shared__ float TXe[EXN * TPS];
    __shared__ float2 RED[256];

    const int tid = threadIdx.x;
    const int col = tid & 15;
    const int oy  = tid >> 4;

    // Gaussian taps (matches np float32: exp(-(i-5)^2/4.5) / sum)
    float g[11];
    {
        float s = 0.f;
#pragma unroll
        for (int i = 0; i < 11; i++) {
            float d = (float)(i - 5);
            g[i] = expf(-d * d / 4.5f);
            s += g[i];
        }
#pragma unroll
        for (int i = 0; i < 11; i++) g[i] /= s;
    }

    // C1/C2 from this level's img1 min/max (computed by preceding kernel)
    const unsigned* wsu = (const unsigned*)wsf;
    float mxv = dec_f(wsu[15 + level]);
    float mnv = dec_f(wsu[10 + level]);
    float maxval = (mxv > 128.f) ? 255.f : 1.f;
    float minval = (mnv < -0.5f) ? -1.f : 0.f;
    float Lr = maxval - minval;
    float C1 = 0.01f * Lr; C1 *= C1;
    float C2 = 0.03f * Lr; C2 *= C2;

    const int ZCn   = (O + ZC - 1) / ZC;
    const int batch = blockIdx.z / ZCn;
    const int oz0   = (blockIdx.z - batch * ZCn) * ZC;
    const int oz1   = min(oz0 + ZC, O);
    const int nplanes = oz1 - oz0 + 10;
    const int ox0   = blockIdx.x * TSX;
    const int oy0   = blockIdx.y * TSY;
    const int D2    = D * D;
    const float* A  = img1 + (long)batch * D * D2;
    const float* B  = img2 + (long)batch * D * D2;

    // per-thread staging slots (plane-invariant offsets); 676 = 26*26 float2
    int  poff[3], sidx[3];
    bool pval[3];
#pragma unroll
    for (int k = 0; k < 3; k++) {
        int idx = tid + (k << 8);
        pval[k] = (idx < EXN * EXN);
        int row = idx / EXN;
        int c   = idx - row * EXN;
        sidx[k] = row * SPS + c;
        int gy = min(oy0 + row, D - 1);
        int gx = min(ox0 + c,   D - 1);
        poff[k] = gy * D + gx;
    }

    float ring[5][11] = {};
    float ssim_acc = 0.f, cs_acc = 0.f;

    const bool vout = (ox0 + col < O) && (oy0 + oy < O);

    // preload first plane
    float2 P[3];
    {
        long zoff = (long)oz0 * D2;
#pragma unroll
        for (int k = 0; k < 3; k++)
            if (pval[k]) P[k] = make_float2(A[zoff + poff[k]], B[zoff + poff[k]]);
    }

    for (int pc = 0; pc < nplanes; ++pc) {
        __syncthreads();  // prior x-conv S-reads & y-conv TX-reads complete
#pragma unroll
        for (int k = 0; k < 3; k++)
            if (pval[k]) S[sidx[k]] = P[k];
        // prefetch next plane
        if (pc + 1 < nplanes) {
            long zoff = (long)(oz0 + pc + 1) * D2;
#pragma unroll
            for (int k = 0; k < 3; k++)
                if (pval[k]) P[k] = make_float2(A[zoff + poff[k]], B[zoff + poff[k]]);
        }
        __syncthreads();

        // ---- x-conv: 208 tasks, each 2 output cols of one ext row
        if (tid < EXN * 8) {
            int row = tid >> 3;
            int cg  = tid & 7;          // c0 = 2*cg
            const float4* srow = (const float4*)(S + row * SPS);
            float pa[12], pb[12];
#pragma unroll
            for (int i = 0; i < 6; i++) {
                float4 q = srow[cg + i];
                pa[2 * i] = q.x; pb[2 * i] = q.y;
                pa[2 * i + 1] = q.z; pb[2 * i + 1] = q.w;
            }
#pragma unroll
            for (int c = 0; c < 2; c++) {
                float m1 = 0.f, m2 = 0.f, aa = 0.f, bb = 0.f, ab = 0.f;
#pragma unroll
                for (int j = 0; j < 11; j++) {
                    float w = g[j];
                    float a = pa[c + j], b = pb[c + j];
                    float wa = w * a, wb = w * b;
                    m1 += wa; m2 += wb;
                    aa += wa * a; bb += wb * b; ab += wa * b;
                }
                int o = row * TPS + 2 * cg + c;
                TX4[o] = make_float4(m1, m2, aa, bb);
                TXe[o] = ab;
            }
        }
        __syncthreads();

        // ---- y-conv (1 owned output row) + ring shift/push
        {
            float s0 = 0.f, s1 = 0.f, s2 = 0.f, s3 = 0.f, s4 = 0.f;
#pragma unroll
            for (int j = 0; j < 11; j++) {
                int o = (oy + j) * TPS + col;
                float4 q = TX4[o];
                float e  = TXe[o];
                float w = g[j];
                s0 += w * q.x; s1 += w * q.y;
                s2 += w * q.z; s3 += w * q.w;
                s4 += w * e;
            }
#pragma unroll
            for (int k = 0; k < 10; k++) {
                ring[0][k] = ring[0][k + 1];
                ring[1][k] = ring[1][k + 1];
                ring[2][k] = ring[2][k + 1];
                ring[3][k] = ring[3][k + 1];
                ring[4][k] = ring[4][k + 1];
            }
            ring[0][10] = s0; ring[1][10] = s1; ring[2][10] = s2;
            ring[3][10] = s3; ring[4][10] = s4;
        }

        // ---- completed output plane
        if (pc >= 10 && vout) {
            float m1 = 0.f, m2 = 0.f, s11 = 0.f, s22 = 0.f, s12 = 0.f;
#pragma unroll
            for (int k = 0; k < 11; k++) {
                float w = g[k];
                m1  += w * ring[0][k];
                m2  += w * ring[1][k];
                s11 += w * ring[2][k];
                s22 += w * ring[3][k];
                s12 += w * ring[4][k];
            }
            float mu11 = m1 * m1, mu22 = m2 * m2, mu12 = m1 * m2;
            float sg1 = s11 - mu11, sg2 = s22 - mu22, sg12 = s12 - mu12;
            float v1 = 2.f * sg12 + C2;
            float v2 = sg1 + sg2 + C2;
            cs_acc   += v1 / v2;
            ssim_acc += ((2.f * mu12 + C1) * v1) / ((mu11 + mu22 + C1) * v2);
        }
    }

    // block reduce + one atomic pair
    RED[tid] = make_float2(ssim_acc, cs_acc);
    __syncthreads();
    for (int s = 128; s > 0; s >>= 1) {
        if (tid < s) {
            RED[tid].x += RED[tid + s].x;
            RED[tid].y += RED[tid + s].y;
        }
        __syncthreads();
    }
    if (tid == 0) {
        atomicAdd(&wsf[level],     RED[0].x);
        atomicAdd(&wsf[5 + level], RED[0].y);
    }
}

__global__ void final_kernel(const float* wsf, float* out,
                             double c0, double c1, double c2, double c3, double c4) {
    if (threadIdx.x != 0 || blockIdx.x != 0) return;
    double cnt[5] = {c0, c1, c2, c3, c4};
    double w[5];
    w[0] = (double)0.0448f; w[1] = (double)0.2856f; w[2] = (double)0.3001f;
    w[3] = (double)0.2363f; w[4] = (double)0.1333f;
    double prod = 1.0;
    for (int l = 0; l < 4; l++) {
        double cs = (double)wsf[5 + l] / cnt[l];
        prod *= pow(cs, w[l]);
    }
    double sm = (double)wsf[4] / cnt[4];
    prod *= pow(sm, w[4]);
    out[0] = (float)prod;
}

extern "C" void kernel_launch(void* const* d_in, const int* in_sizes, int n_in,
                              void* d_out, int out_size, void* d_ws, size_t ws_size,
                              hipStream_t stream) {
    (void)in_sizes; (void)n_in; (void)out_size; (void)ws_size;
    const float* img1 = (const float*)d_in[0];
    const float* img2 = (const float*)d_in[1];
    float*    wsf = (float*)d_ws;
    unsigned* wsu = (unsigned*)d_ws;
    float*    out = (float*)d_out;

    const int Ds[5]  = {192, 96, 48, 24, 12};
    // z-chunk per level: balance halo amortization vs block-count parallelism
    const int ZCs[5] = {46, 22, 5, 2, 2};

    // pyramid buffers in workspace
    float* bufA[5] = {nullptr};
    float* bufB[5] = {nullptr};
    size_t o = 32;
    for (int l = 1; l < 5; l++) {
        long n = 2L * Ds[l] * Ds[l] * Ds[l];
        bufA[l] = wsf + o; o += (size_t)n;
        bufB[l] = wsf + o; o += (size_t)n;
    }

    init_kernel<<<1, 64, 0, stream>>>(wsf);

    long n0 = 2L * 192 * 192 * 192;
    minmax_kernel<<<2048, 256, 0, stream>>>((const float4*)img1, n0 / 4, wsu, 0);

    const float* pA = img1;
    const float* pB = img2;
    for (int l = 0; l < 5; l++) {
        int D = Ds[l], O = D - 10, ZC = ZCs[l];
        int ZCn = (O + ZC - 1) / ZC;
        dim3 grid((O + TSX - 1) / TSX, (O + TSY - 1) / TSY, 2 * ZCn);
        ssim_kernel<<<grid, dim3(256), 0, stream>>>(pA, pB, D, O, ZC, wsf, l);
        if (l < 4) {
            int Dh = Ds[l + 1];
            long n = 2L * Dh * Dh * Dh;
            pool_kernel<<<(int)((n + 255) / 256), 256, 0, stream>>>(
                pA, pB, bufA[l + 1], bufB[l + 1], D, Dh, (int)n, wsu, l + 1);
            pA = bufA[l + 1];
            pB = bufB[l + 1];
        }
    }

    double cnts[5];
    for (int l = 0; l < 5; l++) {
        double Od = (double)(Ds[l] - 10);
        cnts[l] = 2.0 * Od * Od * Od;
    }
    final_kernel<<<1, 64, 0, stream>>>(wsf, out, cnts[0], cnts[1], cnts[2], cnts[3], cnts[4]);
}

// Round 3
// 518.441 us; speedup vs baseline: 1.7451x; 1.1998x over previous
//
#include <hip/hip_runtime.h>
#include <math.h>

// ---------------------------------------------------------------------------
// MS-SSIM 3D (window 11, sigma 1.5, 5 levels) for (2,1,192,192,192) fp32 pairs.
//
// ws float layout:
//   [0..4]   ssim_sum[level]      (float atomics)
//   [5..9]   cs_sum[level]        (float atomics)
//   [10..14] min_enc[level]       (sortable-uint atomicMin)
//   [15..19] max_enc[level]       (sortable-uint atomicMax)
//   [32.. ]  pyramid images (levels 1..4, img1 then img2 per level)
//
// R3: build the whole pyramid first (pools are cheap), then run ALL levels'
// SSIM blocks in ONE dispatch so tail levels ride along with level 0 instead
// of running as serial latency-bound mini-dispatches.
// ---------------------------------------------------------------------------

__device__ __forceinline__ unsigned enc_f(float f) {
    unsigned u = __float_as_uint(f);
    return (u & 0x80000000u) ? ~u : (u | 0x80000000u);
}
__device__ __forceinline__ float dec_f(unsigned e) {
    unsigned u = (e & 0x80000000u) ? (e ^ 0x80000000u) : ~e;
    return __uint_as_float(u);
}

__global__ void init_kernel(float* wsf) {
    unsigned* wsu = (unsigned*)wsf;
    int t = threadIdx.x;
    if (t < 10)       wsf[t] = 0.0f;
    else if (t < 15)  wsu[t] = 0xFFFFFFFFu;  // min slots
    else if (t < 20)  wsu[t] = 0u;           // max slots
}

__global__ void minmax_kernel(const float4* __restrict__ in, long n4,
                              unsigned* wsu, int lvl) {
    float mn = INFINITY, mx = -INFINITY;
    long stride = (long)gridDim.x * blockDim.x;
    for (long i = (long)blockIdx.x * blockDim.x + threadIdx.x; i < n4; i += stride) {
        float4 v = in[i];
        mn = fminf(mn, fminf(fminf(v.x, v.y), fminf(v.z, v.w)));
        mx = fmaxf(mx, fmaxf(fmaxf(v.x, v.y), fmaxf(v.z, v.w)));
    }
    for (int o = 32; o; o >>= 1) {
        mn = fminf(mn, __shfl_down(mn, o));
        mx = fmaxf(mx, __shfl_down(mx, o));
    }
    __shared__ float smn[4], smx[4];
    int lane = threadIdx.x & 63, w = threadIdx.x >> 6;
    if (lane == 0) { smn[w] = mn; smx[w] = mx; }
    __syncthreads();
    if (threadIdx.x == 0) {
        for (int i = 1; i < 4; i++) { mn = fminf(mn, smn[i]); mx = fmaxf(mx, smx[i]); }
        atomicMin(&wsu[10 + lvl], enc_f(mn));
        atomicMax(&wsu[15 + lvl], enc_f(mx));
    }
}

// 2x2x2 avg pool of both images; fused min/max of pooled img1 -> slot lvl_next.
__global__ void pool_kernel(const float* __restrict__ i1, const float* __restrict__ i2,
                            float* __restrict__ o1, float* __restrict__ o2,
                            int D, int Dh, int n, unsigned* wsu, int lvl_next) {
    int idx = blockIdx.x * blockDim.x + threadIdx.x;
    float vmn = INFINITY, vmx = -INFINITY;
    if (idx < n) {
        int Dh2 = Dh * Dh;
        int Dh3 = Dh2 * Dh;
        int b = idx / Dh3; int r = idx - b * Dh3;
        int z = r / Dh2;   r -= z * Dh2;
        int y = r / Dh;    int x = r - y * Dh;
        long base = (long)b * D * D * D + (long)(2 * z) * D * D + (long)(2 * y) * D + 2 * x;
        float2 a00 = *(const float2*)(i1 + base);
        float2 a01 = *(const float2*)(i1 + base + D);
        float2 a10 = *(const float2*)(i1 + base + (long)D * D);
        float2 a11 = *(const float2*)(i1 + base + (long)D * D + D);
        float s1 = (a00.x + a00.y + a01.x + a01.y + a10.x + a10.y + a11.x + a11.y) * 0.125f;
        float2 b00 = *(const float2*)(i2 + base);
        float2 b01 = *(const float2*)(i2 + base + D);
        float2 b10 = *(const float2*)(i2 + base + (long)D * D);
        float2 b11 = *(const float2*)(i2 + base + (long)D * D + D);
        float s2 = (b00.x + b00.y + b01.x + b01.y + b10.x + b10.y + b11.x + b11.y) * 0.125f;
        o1[idx] = s1;
        o2[idx] = s2;
        vmn = s1; vmx = s1;
    }
    for (int o = 32; o; o >>= 1) {
        vmn = fminf(vmn, __shfl_down(vmn, o));
        vmx = fmaxf(vmx, __shfl_down(vmx, o));
    }
    __shared__ float smn[4], smx[4];
    int lane = threadIdx.x & 63, w = threadIdx.x >> 6;
    if (lane == 0) { smn[w] = vmn; smx[w] = vmx; }
    __syncthreads();
    if (threadIdx.x == 0) {
        for (int i = 1; i < 4; i++) { vmn = fminf(vmn, smn[i]); vmx = fmaxf(vmx, smx[i]); }
        atomicMin(&wsu[10 + lvl_next], enc_f(vmn));
        atomicMax(&wsu[15 + lvl_next], enc_f(vmx));
    }
}

// ---------------------------------------------------------------------------
// Combined SSIM kernel: one dispatch, all 5 levels. Per block a 16x16 output
// tile swept over a z-chunk. Per input plane: stage (a,b) ext tile in LDS ->
// x-conv of 5 fields (packed float4+float) -> y-conv -> z via 55-reg ring.
// ---------------------------------------------------------------------------
#define TSX 16
#define TSY 16
#define EXN 26            // ext rows/cols (16+10)
#define SPS 28            // S row stride in float2 (16B aligned rows)
#define TPS 17            // TX row stride in elements

struct AllParams {
    const float* A[5];
    const float* B[5];
    int D[5], O[5], zc[5], nT[5], ZCn[5];
    int blk0[6];          // cumulative block offsets, level order 0..4
};

__launch_bounds__(256, 3)
__global__ void ssim_all_kernel(AllParams P, float* wsf) {
    __shared__ __align__(16) float2 S[EXN * SPS];
    __shared__ __align__(16) float4 TX4[EXN * TPS];
    __shared__ float TXe[EXN * TPS];
    __shared__ float2 RED[256];

    const int tid = threadIdx.x;
    const int col = tid & 15;
    const int oy  = tid >> 4;

    // ---- decode level + tile from flat blockIdx.x
    int level = 0;
    {
        int b = blockIdx.x;
#pragma unroll
        for (int l = 1; l < 5; l++)
            if (b >= P.blk0[l]) level = l;
    }
    const int rel = blockIdx.x - P.blk0[level];
    const int D   = P.D[level];
    const int O   = P.O[level];
    const int ZC  = P.zc[level];
    const int nT  = P.nT[level];
    const int ZCn = P.ZCn[level];

    int t  = rel;
    const int tx = t % nT;  t /= nT;
    const int tyi = t % nT; t /= nT;
    const int batch = t % 2; t /= 2;
    const int chunk = t;

    const int oz0 = chunk * ZC;
    const int oz1 = min(oz0 + ZC, O);
    const int nplanes = oz1 - oz0 + 10;
    const int ox0 = tx * TSX;
    const int oy0 = tyi * TSY;
    const int D2  = D * D;
    const float* A = P.A[level] + (long)batch * D * D2;
    const float* B = P.B[level] + (long)batch * D * D2;
    (void)ZCn;

    // Gaussian taps (matches np float32: exp(-(i-5)^2/4.5) / sum)
    float g[11];
    {
        float s = 0.f;
#pragma unroll
        for (int i = 0; i < 11; i++) {
            float d = (float)(i - 5);
            g[i] = expf(-d * d / 4.5f);
            s += g[i];
        }
#pragma unroll
        for (int i = 0; i < 11; i++) g[i] /= s;
    }

    // C1/C2 from this level's img1 min/max (computed by pool/minmax kernels)
    const unsigned* wsu = (const unsigned*)wsf;
    float mxv = dec_f(wsu[15 + level]);
    float mnv = dec_f(wsu[10 + level]);
    float maxval = (mxv > 128.f) ? 255.f : 1.f;
    float minval = (mnv < -0.5f) ? -1.f : 0.f;
    float Lr = maxval - minval;
    float C1 = 0.01f * Lr; C1 *= C1;
    float C2 = 0.03f * Lr; C2 *= C2;

    // per-thread staging slots (plane-invariant offsets); 676 = 26*26
    int  poff[3], sidx[3];
    bool pval[3];
#pragma unroll
    for (int k = 0; k < 3; k++) {
        int idx = tid + (k << 8);
        pval[k] = (idx < EXN * EXN);
        int row = idx / EXN;
        int c   = idx - row * EXN;
        sidx[k] = row * SPS + c;
        int gy = min(oy0 + row, D - 1);
        int gx = min(ox0 + c,   D - 1);
        poff[k] = gy * D + gx;
    }

    float ring[5][11] = {};
    float ssim_acc = 0.f, cs_acc = 0.f;

    const bool vout = (ox0 + col < O) && (oy0 + oy < O);

    // preload first plane
    float2 Pld[3];
    {
        long zoff = (long)oz0 * D2;
#pragma unroll
        for (int k = 0; k < 3; k++)
            if (pval[k]) Pld[k] = make_float2(A[zoff + poff[k]], B[zoff + poff[k]]);
    }

    for (int pc = 0; pc < nplanes; ++pc) {
        __syncthreads();  // prior x-conv S-reads & y-conv TX-reads complete
#pragma unroll
        for (int k = 0; k < 3; k++)
            if (pval[k]) S[sidx[k]] = Pld[k];
        // prefetch next plane
        if (pc + 1 < nplanes) {
            long zoff = (long)(oz0 + pc + 1) * D2;
#pragma unroll
            for (int k = 0; k < 3; k++)
                if (pval[k]) Pld[k] = make_float2(A[zoff + poff[k]], B[zoff + poff[k]]);
        }
        __syncthreads();

        // ---- x-conv: 208 tasks, each 2 output cols of one ext row
        if (tid < EXN * 8) {
            int row = tid >> 3;
            int cg  = tid & 7;          // c0 = 2*cg
            const float4* srow = (const float4*)(S + row * SPS);
            float pa[12], pb[12];
#pragma unroll
            for (int i = 0; i < 6; i++) {
                float4 q = srow[cg + i];
                pa[2 * i] = q.x; pb[2 * i] = q.y;
                pa[2 * i + 1] = q.z; pb[2 * i + 1] = q.w;
            }
#pragma unroll
            for (int c = 0; c < 2; c++) {
                float m1 = 0.f, m2 = 0.f, aa = 0.f, bb = 0.f, ab = 0.f;
#pragma unroll
                for (int j = 0; j < 11; j++) {
                    float w = g[j];
                    float a = pa[c + j], b = pb[c + j];
                    float wa = w * a, wb = w * b;
                    m1 += wa; m2 += wb;
                    aa += wa * a; bb += wb * b; ab += wa * b;
                }
                int o = row * TPS + 2 * cg + c;
                TX4[o] = make_float4(m1, m2, aa, bb);
                TXe[o] = ab;
            }
        }
        __syncthreads();

        // ---- y-conv (1 owned output row) + ring shift/push
        {
            float s0 = 0.f, s1 = 0.f, s2 = 0.f, s3 = 0.f, s4 = 0.f;
#pragma unroll
            for (int j = 0; j < 11; j++) {
                int o = (oy + j) * TPS + col;
                float4 q = TX4[o];
                float e  = TXe[o];
                float w = g[j];
                s0 += w * q.x; s1 += w * q.y;
                s2 += w * q.z; s3 += w * q.w;
                s4 += w * e;
            }
#pragma unroll
            for (int k = 0; k < 10; k++) {
                ring[0][k] = ring[0][k + 1];
                ring[1][k] = ring[1][k + 1];
                ring[2][k] = ring[2][k + 1];
                ring[3][k] = ring[3][k + 1];
                ring[4][k] = ring[4][k + 1];
            }
            ring[0][10] = s0; ring[1][10] = s1; ring[2][10] = s2;
            ring[3][10] = s3; ring[4][10] = s4;
        }

        // ---- completed output plane
        if (pc >= 10 && vout) {
            float m1 = 0.f, m2 = 0.f, s11 = 0.f, s22 = 0.f, s12 = 0.f;
#pragma unroll
            for (int k = 0; k < 11; k++) {
                float w = g[k];
                m1  += w * ring[0][k];
                m2  += w * ring[1][k];
                s11 += w * ring[2][k];
                s22 += w * ring[3][k];
                s12 += w * ring[4][k];
            }
            float mu11 = m1 * m1, mu22 = m2 * m2, mu12 = m1 * m2;
            float sg1 = s11 - mu11, sg2 = s22 - mu22, sg12 = s12 - mu12;
            float v1 = 2.f * sg12 + C2;
            float v2 = sg1 + sg2 + C2;
            cs_acc   += v1 / v2;
            ssim_acc += ((2.f * mu12 + C1) * v1) / ((mu11 + mu22 + C1) * v2);
        }
    }

    // block reduce + one atomic pair
    RED[tid] = make_float2(ssim_acc, cs_acc);
    __syncthreads();
    for (int s = 128; s > 0; s >>= 1) {
        if (tid < s) {
            RED[tid].x += RED[tid + s].x;
            RED[tid].y += RED[tid + s].y;
        }
        __syncthreads();
    }
    if (tid == 0) {
        atomicAdd(&wsf[level],     RED[0].x);
        atomicAdd(&wsf[5 + level], RED[0].y);
    }
}

__global__ void final_kernel(const float* wsf, float* out,
                             double c0, double c1, double c2, double c3, double c4) {
    if (threadIdx.x != 0 || blockIdx.x != 0) return;
    double cnt[5] = {c0, c1, c2, c3, c4};
    double w[5];
    w[0] = (double)0.0448f; w[1] = (double)0.2856f; w[2] = (double)0.3001f;
    w[3] = (double)0.2363f; w[4] = (double)0.1333f;
    double prod = 1.0;
    for (int l = 0; l < 4; l++) {
        double cs = (double)wsf[5 + l] / cnt[l];
        prod *= pow(cs, w[l]);
    }
    double sm = (double)wsf[4] / cnt[4];
    prod *= pow(sm, w[4]);
    out[0] = (float)prod;
}

extern "C" void kernel_launch(void* const* d_in, const int* in_sizes, int n_in,
                              void* d_out, int out_size, void* d_ws, size_t ws_size,
                              hipStream_t stream) {
    (void)in_sizes; (void)n_in; (void)out_size; (void)ws_size;
    const float* img1 = (const float*)d_in[0];
    const float* img2 = (const float*)d_in[1];
    float*    wsf = (float*)d_ws;
    unsigned* wsu = (unsigned*)d_ws;
    float*    out = (float*)d_out;

    const int Ds[5]  = {192, 96, 48, 24, 12};
    // z-chunk per level: minimize halo plane-iters; parallelism comes from the
    // combined dispatch, not per-level grids.
    const int ZCs[5] = {46, 43, 19, 14, 2};

    // pyramid buffers in workspace
    float* bufA[5] = {nullptr};
    float* bufB[5] = {nullptr};
    size_t o = 32;
    for (int l = 1; l < 5; l++) {
        long n = 2L * Ds[l] * Ds[l] * Ds[l];
        bufA[l] = wsf + o; o += (size_t)n;
        bufB[l] = wsf + o; o += (size_t)n;
    }

    init_kernel<<<1, 64, 0, stream>>>(wsf);

    long n0 = 2L * 192 * 192 * 192;
    minmax_kernel<<<2048, 256, 0, stream>>>((const float4*)img1, n0 / 4, wsu, 0);

    // ---- build the whole pyramid up front (cheap, memory-bound)
    const float* pA = img1;
    const float* pB = img2;
    for (int l = 0; l < 4; l++) {
        int D = Ds[l], Dh = Ds[l + 1];
        long n = 2L * Dh * Dh * Dh;
        pool_kernel<<<(int)((n + 255) / 256), 256, 0, stream>>>(
            pA, pB, bufA[l + 1], bufB[l + 1], D, Dh, (int)n, wsu, l + 1);
        pA = bufA[l + 1];
        pB = bufB[l + 1];
    }

    // ---- one combined SSIM dispatch over all 5 levels
    AllParams P;
    P.A[0] = img1; P.B[0] = img2;
    for (int l = 1; l < 5; l++) { P.A[l] = bufA[l]; P.B[l] = bufB[l]; }
    int acc = 0;
    for (int l = 0; l < 5; l++) {
        int D = Ds[l], O = D - 10, ZC = ZCs[l];
        int nT = (O + TSX - 1) / TSX;
        int ZCn = (O + ZC - 1) / ZC;
        P.D[l] = D; P.O[l] = O; P.zc[l] = ZC; P.nT[l] = nT; P.ZCn[l] = ZCn;
        P.blk0[l] = acc;
        acc += nT * nT * 2 * ZCn;
    }
    P.blk0[5] = acc;
    ssim_all_kernel<<<acc, 256, 0, stream>>>(P, wsf);

    double cnts[5];
    for (int l = 0; l < 5; l++) {
        double Od = (double)(Ds[l] - 10);
        cnts[l] = 2.0 * Od * Od * Od;
    }
    final_kernel<<<1, 64, 0, stream>>>(wsf, out, cnts[0], cnts[1], cnts[2], cnts[3], cnts[4]);
}

// Round 4
// 407.721 us; speedup vs baseline: 2.2190x; 1.2716x over previous
//
#include <hip/hip_runtime.h>
#include <math.h>

// ---------------------------------------------------------------------------
// MS-SSIM 3D (window 11, sigma 1.5, 5 levels) for (2,1,192,192,192) fp32 pairs.
//
// ws float layout:
//   [0..4]   ssim_sum[level]      (float atomics)
//   [5..9]   cs_sum[level]        (float atomics)
//   [10..14] min_enc[level]       (sortable-uint atomicMin)
//   [15..19] max_enc[level]       (sortable-uint atomicMax)
//   [32.. ]  pyramid images (levels 1..4, img1 then img2 per level)
//
// R4: single pyramid_kernel builds all pooled levels + all 5 min/max pairs
// (replaces minmax + 4 pool dispatches); then ONE ssim dispatch for all levels.
// ---------------------------------------------------------------------------

__device__ __forceinline__ unsigned enc_f(float f) {
    unsigned u = __float_as_uint(f);
    return (u & 0x80000000u) ? ~u : (u | 0x80000000u);
}
__device__ __forceinline__ float dec_f(unsigned e) {
    unsigned u = (e & 0x80000000u) ? (e ^ 0x80000000u) : ~e;
    return __uint_as_float(u);
}

__global__ void init_kernel(float* wsf) {
    unsigned* wsu = (unsigned*)wsf;
    int t = threadIdx.x;
    if (t < 10)       wsf[t] = 0.0f;
    else if (t < 15)  wsu[t] = 0xFFFFFFFFu;  // min slots
    else if (t < 20)  wsu[t] = 0u;           // max slots
}

// ---------------------------------------------------------------------------
// Fused pyramid: each block owns a 32^3 region of level 0 for one (img,batch),
// produces 16^3 of L1 (regs), 8^3 of L2, 4^3 of L3, 2^3 of L4 via LDS, writes
// all levels to global, and block-reduces min/max per level (img1 only).
// Grid: 216 regions * 2 batches * 2 images = 864 blocks.
// ---------------------------------------------------------------------------
struct PyrParams {
    const float* src[2];   // img1, img2
    float* dst[2][4];      // [img][level-1]
};

__launch_bounds__(256, 4)
__global__ void pyramid_kernel(PyrParams P, float* wsf) {
    __shared__ float L1[16 * 256];   // 16^3
    __shared__ float L2[512];        // 8^3
    __shared__ float L3[64];         // 4^3
    __shared__ float smn[4], smx[4];
    unsigned* wsu = (unsigned*)wsf;

    const int tid = threadIdx.x;
    int blk = blockIdx.x;
    int r = blk % 216; blk /= 216;
    int batch = blk & 1;
    int im = blk >> 1;
    const int rx = r % 6, ry = (r / 6) % 6, rz = r / 36;

    const long N0 = 192L * 192 * 192;
    const float* src = P.src[im] + (long)batch * N0;
    float* d1 = P.dst[im][0] + (long)batch * 96 * 96 * 96;
    float* d2 = P.dst[im][1] + (long)batch * 48 * 48 * 48;
    float* d3 = P.dst[im][2] + (long)batch * 24 * 24 * 24;
    float* d4 = P.dst[im][3] + (long)batch * 12 * 12 * 12;

    const int tx = tid & 15, ty = tid >> 4;
    float mnv[5], mxv[5];
#pragma unroll
    for (int l = 0; l < 5; l++) { mnv[l] = INFINITY; mxv[l] = -INFINITY; }

    // ---- level 1 (16 outputs/thread) + level-0 min/max from raw loads
    const long D = 192, D2 = 192L * 192;
    const int gx = 2 * (rx * 16 + tx);
    const int gy = 2 * (ry * 16 + ty);
#pragma unroll 4
    for (int z = 0; z < 16; z++) {
        const int gz = 2 * (rz * 16 + z);
        long base = (long)gz * D2 + (long)gy * D + gx;
        float2 a00 = *(const float2*)(src + base);
        float2 a01 = *(const float2*)(src + base + D);
        float2 a10 = *(const float2*)(src + base + D2);
        float2 a11 = *(const float2*)(src + base + D2 + D);
        float lo = fminf(fminf(fminf(a00.x, a00.y), fminf(a01.x, a01.y)),
                         fminf(fminf(a10.x, a10.y), fminf(a11.x, a11.y)));
        float hi = fmaxf(fmaxf(fmaxf(a00.x, a00.y), fmaxf(a01.x, a01.y)),
                         fmaxf(fmaxf(a10.x, a10.y), fmaxf(a11.x, a11.y)));
        mnv[0] = fminf(mnv[0], lo); mxv[0] = fmaxf(mxv[0], hi);
        float s = (a00.x + a00.y + a01.x + a01.y +
                   a10.x + a10.y + a11.x + a11.y) * 0.125f;
        mnv[1] = fminf(mnv[1], s); mxv[1] = fmaxf(mxv[1], s);
        d1[(long)(rz * 16 + z) * 96 * 96 + (ry * 16 + ty) * 96 + (rx * 16 + tx)] = s;
        L1[z * 256 + ty * 16 + tx] = s;
    }
    __syncthreads();

    // ---- level 2 (2 outputs/thread)
    float v2[2];
#pragma unroll
    for (int k = 0; k < 2; k++) {
        int o = tid + (k << 8);
        int x = o & 7, y = (o >> 3) & 7, z = o >> 6;
        float s = (L1[(2 * z) * 256 + (2 * y) * 16 + 2 * x] +
                   L1[(2 * z) * 256 + (2 * y) * 16 + 2 * x + 1] +
                   L1[(2 * z) * 256 + (2 * y + 1) * 16 + 2 * x] +
                   L1[(2 * z) * 256 + (2 * y + 1) * 16 + 2 * x + 1] +
                   L1[(2 * z + 1) * 256 + (2 * y) * 16 + 2 * x] +
                   L1[(2 * z + 1) * 256 + (2 * y) * 16 + 2 * x + 1] +
                   L1[(2 * z + 1) * 256 + (2 * y + 1) * 16 + 2 * x] +
                   L1[(2 * z + 1) * 256 + (2 * y + 1) * 16 + 2 * x + 1]) * 0.125f;
        v2[k] = s;
        mnv[2] = fminf(mnv[2], s); mxv[2] = fmaxf(mxv[2], s);
        d2[(long)(rz * 8 + z) * 48 * 48 + (ry * 8 + y) * 48 + (rx * 8 + x)] = s;
        L2[o] = s;
    }
    __syncthreads();

    // ---- level 3 (first 64 threads)
    if (tid < 64) {
        int x = tid & 3, y = (tid >> 2) & 3, z = tid >> 4;
        float s = (L2[(2 * z) * 64 + (2 * y) * 8 + 2 * x] +
                   L2[(2 * z) * 64 + (2 * y) * 8 + 2 * x + 1] +
                   L2[(2 * z) * 64 + (2 * y + 1) * 8 + 2 * x] +
                   L2[(2 * z) * 64 + (2 * y + 1) * 8 + 2 * x + 1] +
                   L2[(2 * z + 1) * 64 + (2 * y) * 8 + 2 * x] +
                   L2[(2 * z + 1) * 64 + (2 * y) * 8 + 2 * x + 1] +
                   L2[(2 * z + 1) * 64 + (2 * y + 1) * 8 + 2 * x] +
                   L2[(2 * z + 1) * 64 + (2 * y + 1) * 8 + 2 * x + 1]) * 0.125f;
        mnv[3] = fminf(mnv[3], s); mxv[3] = fmaxf(mxv[3], s);
        d3[(long)(rz * 4 + z) * 24 * 24 + (ry * 4 + y) * 24 + (rx * 4 + x)] = s;
        L3[tid] = s;
    }
    __syncthreads();

    // ---- level 4 (first 8 threads)
    if (tid < 8) {
        int x = tid & 1, y = (tid >> 1) & 1, z = tid >> 2;
        float s = (L3[(2 * z) * 16 + (2 * y) * 4 + 2 * x] +
                   L3[(2 * z) * 16 + (2 * y) * 4 + 2 * x + 1] +
                   L3[(2 * z) * 16 + (2 * y + 1) * 4 + 2 * x] +
                   L3[(2 * z) * 16 + (2 * y + 1) * 4 + 2 * x + 1] +
                   L3[(2 * z + 1) * 16 + (2 * y) * 4 + 2 * x] +
                   L3[(2 * z + 1) * 16 + (2 * y) * 4 + 2 * x + 1] +
                   L3[(2 * z + 1) * 16 + (2 * y + 1) * 4 + 2 * x] +
                   L3[(2 * z + 1) * 16 + (2 * y + 1) * 4 + 2 * x + 1]) * 0.125f;
        mnv[4] = fminf(mnv[4], s); mxv[4] = fmaxf(mxv[4], s);
        d4[(long)(rz * 2 + z) * 12 * 12 + (ry * 2 + y) * 12 + (rx * 2 + x)] = s;
    }

    // ---- per-level block min/max reduce; atomics only from img1 blocks
    const int lane = tid & 63, w = tid >> 6;
#pragma unroll
    for (int l = 0; l < 5; l++) {
        float mn = mnv[l], mx = mxv[l];
        for (int o = 32; o; o >>= 1) {
            mn = fminf(mn, __shfl_down(mn, o));
            mx = fmaxf(mx, __shfl_down(mx, o));
        }
        __syncthreads();
        if (lane == 0) { smn[w] = mn; smx[w] = mx; }
        __syncthreads();
        if (tid == 0 && im == 0) {
            for (int i = 1; i < 4; i++) { mn = fminf(mn, smn[i]); mx = fmaxf(mx, smx[i]); }
            atomicMin(&wsu[10 + l], enc_f(mn));
            atomicMax(&wsu[15 + l], enc_f(mx));
        }
    }
}

// ---------------------------------------------------------------------------
// Combined SSIM kernel: one dispatch, all 5 levels. Per block a 16x16 output
// tile swept over a z-chunk. Per input plane: stage (a,b) ext tile in LDS ->
// x-conv of 5 fields (packed float4+float) -> y-conv -> z via 55-reg ring.
// ---------------------------------------------------------------------------
#define TSX 16
#define TSY 16
#define EXN 26            // ext rows/cols (16+10)
#define SPS 28            // S row stride in float2 (16B aligned rows)
#define TPS 17            // TX row stride in elements

struct AllParams {
    const float* A[5];
    const float* B[5];
    int D[5], O[5], zc[5], nT[5], ZCn[5];
    int blk0[6];          // cumulative block offsets, level order 0..4
};

__launch_bounds__(256, 3)
__global__ void ssim_all_kernel(AllParams P, float* wsf) {
    __shared__ __align__(16) float2 S[EXN * SPS];
    __shared__ __align__(16) float4 TX4[EXN * TPS];
    __shared__ float TXe[EXN * TPS];
    __shared__ float2 RED[256];

    const int tid = threadIdx.x;
    const int col = tid & 15;
    const int oy  = tid >> 4;

    // ---- decode level + tile from flat blockIdx.x
    int level = 0;
    {
        int b = blockIdx.x;
#pragma unroll
        for (int l = 1; l < 5; l++)
            if (b >= P.blk0[l]) level = l;
    }
    const int rel = blockIdx.x - P.blk0[level];
    const int D   = P.D[level];
    const int O   = P.O[level];
    const int ZC  = P.zc[level];
    const int nT  = P.nT[level];

    int t  = rel;
    const int tx = t % nT;  t /= nT;
    const int tyi = t % nT; t /= nT;
    const int batch = t % 2; t /= 2;
    const int chunk = t;

    const int oz0 = chunk * ZC;
    const int oz1 = min(oz0 + ZC, O);
    const int nplanes = oz1 - oz0 + 10;
    const int ox0 = tx * TSX;
    const int oy0 = tyi * TSY;
    const int D2  = D * D;
    const float* A = P.A[level] + (long)batch * D * D2;
    const float* B = P.B[level] + (long)batch * D * D2;

    // Gaussian taps (matches np float32: exp(-(i-5)^2/4.5) / sum)
    float g[11];
    {
        float s = 0.f;
#pragma unroll
        for (int i = 0; i < 11; i++) {
            float d = (float)(i - 5);
            g[i] = expf(-d * d / 4.5f);
            s += g[i];
        }
#pragma unroll
        for (int i = 0; i < 11; i++) g[i] /= s;
    }

    // C1/C2 from this level's img1 min/max (computed by pyramid kernel)
    const unsigned* wsu = (const unsigned*)wsf;
    float mxv = dec_f(wsu[15 + level]);
    float mnv = dec_f(wsu[10 + level]);
    float maxval = (mxv > 128.f) ? 255.f : 1.f;
    float minval = (mnv < -0.5f) ? -1.f : 0.f;
    float Lr = maxval - minval;
    float C1 = 0.01f * Lr; C1 *= C1;
    float C2 = 0.03f * Lr; C2 *= C2;

    // per-thread staging slots (plane-invariant offsets); 676 = 26*26
    int  poff[3], sidx[3];
    bool pval[3];
#pragma unroll
    for (int k = 0; k < 3; k++) {
        int idx = tid + (k << 8);
        pval[k] = (idx < EXN * EXN);
        int row = idx / EXN;
        int c   = idx - row * EXN;
        sidx[k] = row * SPS + c;
        int gy = min(oy0 + row, D - 1);
        int gx = min(ox0 + c,   D - 1);
        poff[k] = gy * D + gx;
    }

    float ring[5][11] = {};
    float ssim_acc = 0.f, cs_acc = 0.f;

    const bool vout = (ox0 + col < O) && (oy0 + oy < O);

    // preload first plane
    float2 Pld[3];
    {
        long zoff = (long)oz0 * D2;
#pragma unroll
        for (int k = 0; k < 3; k++)
            if (pval[k]) Pld[k] = make_float2(A[zoff + poff[k]], B[zoff + poff[k]]);
    }

    for (int pc = 0; pc < nplanes; ++pc) {
        __syncthreads();  // prior x-conv S-reads & y-conv TX-reads complete
#pragma unroll
        for (int k = 0; k < 3; k++)
            if (pval[k]) S[sidx[k]] = Pld[k];
        // prefetch next plane
        if (pc + 1 < nplanes) {
            long zoff = (long)(oz0 + pc + 1) * D2;
#pragma unroll
            for (int k = 0; k < 3; k++)
                if (pval[k]) Pld[k] = make_float2(A[zoff + poff[k]], B[zoff + poff[k]]);
        }
        __syncthreads();

        // ---- x-conv: 208 tasks, each 2 output cols of one ext row
        if (tid < EXN * 8) {
            int row = tid >> 3;
            int cg  = tid & 7;          // c0 = 2*cg
            const float4* srow = (const float4*)(S + row * SPS);
            float pa[12], pb[12];
#pragma unroll
            for (int i = 0; i < 6; i++) {
                float4 q = srow[cg + i];
                pa[2 * i] = q.x; pb[2 * i] = q.y;
                pa[2 * i + 1] = q.z; pb[2 * i + 1] = q.w;
            }
#pragma unroll
            for (int c = 0; c < 2; c++) {
                float m1 = 0.f, m2 = 0.f, aa = 0.f, bb = 0.f, ab = 0.f;
#pragma unroll
                for (int j = 0; j < 11; j++) {
                    float w = g[j];
                    float a = pa[c + j], b = pb[c + j];
                    float wa = w * a, wb = w * b;
                    m1 += wa; m2 += wb;
                    aa += wa * a; bb += wb * b; ab += wa * b;
                }
                int o = row * TPS + 2 * cg + c;
                TX4[o] = make_float4(m1, m2, aa, bb);
                TXe[o] = ab;
            }
        }
        __syncthreads();

        // ---- y-conv (1 owned output row) + ring shift/push
        {
            float s0 = 0.f, s1 = 0.f, s2 = 0.f, s3 = 0.f, s4 = 0.f;
#pragma unroll
            for (int j = 0; j < 11; j++) {
                int o = (oy + j) * TPS + col;
                float4 q = TX4[o];
                float e  = TXe[o];
                float w = g[j];
                s0 += w * q.x; s1 += w * q.y;
                s2 += w * q.z; s3 += w * q.w;
                s4 += w * e;
            }
#pragma unroll
            for (int k = 0; k < 10; k++) {
                ring[0][k] = ring[0][k + 1];
                ring[1][k] = ring[1][k + 1];
                ring[2][k] = ring[2][k + 1];
                ring[3][k] = ring[3][k + 1];
                ring[4][k] = ring[4][k + 1];
            }
            ring[0][10] = s0; ring[1][10] = s1; ring[2][10] = s2;
            ring[3][10] = s3; ring[4][10] = s4;
        }

        // ---- completed output plane
        if (pc >= 10 && vout) {
            float m1 = 0.f, m2 = 0.f, s11 = 0.f, s22 = 0.f, s12 = 0.f;
#pragma unroll
            for (int k = 0; k < 11; k++) {
                float w = g[k];
                m1  += w * ring[0][k];
                m2  += w * ring[1][k];
                s11 += w * ring[2][k];
                s22 += w * ring[3][k];
                s12 += w * ring[4][k];
            }
            float mu11 = m1 * m1, mu22 = m2 * m2, mu12 = m1 * m2;
            float sg1 = s11 - mu11, sg2 = s22 - mu22, sg12 = s12 - mu12;
            float v1 = 2.f * sg12 + C2;
            float v2 = sg1 + sg2 + C2;
            cs_acc   += v1 / v2;
            ssim_acc += ((2.f * mu12 + C1) * v1) / ((mu11 + mu22 + C1) * v2);
        }
    }

    // block reduce + one atomic pair
    RED[tid] = make_float2(ssim_acc, cs_acc);
    __syncthreads();
    for (int s = 128; s > 0; s >>= 1) {
        if (tid < s) {
            RED[tid].x += RED[tid + s].x;
            RED[tid].y += RED[tid + s].y;
        }
        __syncthreads();
    }
    if (tid == 0) {
        atomicAdd(&wsf[level],     RED[0].x);
        atomicAdd(&wsf[5 + level], RED[0].y);
    }
}

__global__ void final_kernel(const float* wsf, float* out,
                             double c0, double c1, double c2, double c3, double c4) {
    if (threadIdx.x != 0 || blockIdx.x != 0) return;
    double cnt[5] = {c0, c1, c2, c3, c4};
    double w[5];
    w[0] = (double)0.0448f; w[1] = (double)0.2856f; w[2] = (double)0.3001f;
    w[3] = (double)0.2363f; w[4] = (double)0.1333f;
    double prod = 1.0;
    for (int l = 0; l < 4; l++) {
        double cs = (double)wsf[5 + l] / cnt[l];
        prod *= pow(cs, w[l]);
    }
    double sm = (double)wsf[4] / cnt[4];
    prod *= pow(sm, w[4]);
    out[0] = (float)prod;
}

extern "C" void kernel_launch(void* const* d_in, const int* in_sizes, int n_in,
                              void* d_out, int out_size, void* d_ws, size_t ws_size,
                              hipStream_t stream) {
    (void)in_sizes; (void)n_in; (void)out_size; (void)ws_size;
    const float* img1 = (const float*)d_in[0];
    const float* img2 = (const float*)d_in[1];
    float* wsf = (float*)d_ws;
    float* out = (float*)d_out;

    const int Ds[5]  = {192, 96, 48, 24, 12};
    const int ZCs[5] = {46, 43, 19, 14, 2};

    // pyramid buffers in workspace
    float* bufA[5] = {nullptr};
    float* bufB[5] = {nullptr};
    size_t o = 32;
    for (int l = 1; l < 5; l++) {
        long n = 2L * Ds[l] * Ds[l] * Ds[l];
        bufA[l] = wsf + o; o += (size_t)n;
        bufB[l] = wsf + o; o += (size_t)n;
    }

    init_kernel<<<1, 64, 0, stream>>>(wsf);

    // ---- one dispatch: entire pyramid + all 5 min/max pairs
    PyrParams PP;
    PP.src[0] = img1; PP.src[1] = img2;
    for (int l = 1; l < 5; l++) { PP.dst[0][l - 1] = bufA[l]; PP.dst[1][l - 1] = bufB[l]; }
    pyramid_kernel<<<216 * 2 * 2, 256, 0, stream>>>(PP, wsf);

    // ---- one combined SSIM dispatch over all 5 levels
    AllParams P;
    P.A[0] = img1; P.B[0] = img2;
    for (int l = 1; l < 5; l++) { P.A[l] = bufA[l]; P.B[l] = bufB[l]; }
    int acc = 0;
    for (int l = 0; l < 5; l++) {
        int D = Ds[l], O = D - 10, ZC = ZCs[l];
        int nT = (O + TSX - 1) / TSX;
        int ZCn = (O + ZC - 1) / ZC;
        P.D[l] = D; P.O[l] = O; P.zc[l] = ZC; P.nT[l] = nT; P.ZCn[l] = ZCn;
        P.blk0[l] = acc;
        acc += nT * nT * 2 * ZCn;
    }
    P.blk0[5] = acc;
    ssim_all_kernel<<<acc, 256, 0, stream>>>(P, wsf);

    double cnts[5];
    for (int l = 0; l < 5; l++) {
        double Od = (double)(Ds[l] - 10);
        cnts[l] = 2.0 * Od * Od * Od;
    }
    final_kernel<<<1, 64, 0, stream>>>(wsf, out, cnts[0], cnts[1], cnts[2], cnts[3], cnts[4]);
}

// Round 5
// 358.578 us; speedup vs baseline: 2.5232x; 1.1371x over previous
//
#include <hip/hip_runtime.h>
#include <math.h>

// ---------------------------------------------------------------------------
// MS-SSIM 3D (window 11, sigma 1.5, 5 levels) for (2,1,192,192,192) fp32 pairs.
//
// ws float layout:
//   [0..4]   ssim_sum[level]      (float atomics)
//   [5..9]   cs_sum[level]        (float atomics)
//   [10..14] min_enc[level]       (sortable-uint atomicMin)
//   [15..19] max_enc[level]       (sortable-uint atomicMax)
//   [20]     completion counter   (uint)
//   [32.. ]  pyramid images (levels 1..4, img1 then img2 per level)
//
// R5: 16x32 tile, 2 output rows/thread (y-read traffic 220->120 B/output),
// systolic z-accumulators (FMA-shift, no ring movs + no epilogue dot),
// conflict-even LDS strides, uniform 36-plane blocks, final fused via counter.
// ---------------------------------------------------------------------------

__device__ __forceinline__ unsigned enc_f(float f) {
    unsigned u = __float_as_uint(f);
    return (u & 0x80000000u) ? ~u : (u | 0x80000000u);
}
__device__ __forceinline__ float dec_f(unsigned e) {
    unsigned u = (e & 0x80000000u) ? (e ^ 0x80000000u) : ~e;
    return __uint_as_float(u);
}

__global__ void init_kernel(float* wsf) {
    unsigned* wsu = (unsigned*)wsf;
    int t = threadIdx.x;
    if (t < 10)       wsf[t] = 0.0f;
    else if (t < 15)  wsu[t] = 0xFFFFFFFFu;  // min slots
    else if (t < 20)  wsu[t] = 0u;           // max slots
    else if (t == 20) wsu[t] = 0u;           // completion counter
}

// ---------------------------------------------------------------------------
// Fused pyramid: each block owns a 32^3 region of level 0 for one (img,batch),
// produces 16^3 of L1 (regs), 8^3 of L2, 4^3 of L3, 2^3 of L4 via LDS, writes
// all levels to global, and block-reduces min/max per level (img1 only).
// ---------------------------------------------------------------------------
struct PyrParams {
    const float* src[2];   // img1, img2
    float* dst[2][4];      // [img][level-1]
};

__launch_bounds__(256, 4)
__global__ void pyramid_kernel(PyrParams P, float* wsf) {
    __shared__ float L1[16 * 256];   // 16^3
    __shared__ float L2[512];        // 8^3
    __shared__ float L3[64];         // 4^3
    __shared__ float smn[4], smx[4];
    unsigned* wsu = (unsigned*)wsf;

    const int tid = threadIdx.x;
    int blk = blockIdx.x;
    int r = blk % 216; blk /= 216;
    int batch = blk & 1;
    int im = blk >> 1;
    const int rx = r % 6, ry = (r / 6) % 6, rz = r / 36;

    const long N0 = 192L * 192 * 192;
    const float* src = P.src[im] + (long)batch * N0;
    float* d1 = P.dst[im][0] + (long)batch * 96 * 96 * 96;
    float* d2 = P.dst[im][1] + (long)batch * 48 * 48 * 48;
    float* d3 = P.dst[im][2] + (long)batch * 24 * 24 * 24;
    float* d4 = P.dst[im][3] + (long)batch * 12 * 12 * 12;

    const int tx = tid & 15, ty = tid >> 4;
    float mnv[5], mxv[5];
#pragma unroll
    for (int l = 0; l < 5; l++) { mnv[l] = INFINITY; mxv[l] = -INFINITY; }

    const long D = 192, D2 = 192L * 192;
    const int gx = 2 * (rx * 16 + tx);
    const int gy = 2 * (ry * 16 + ty);
#pragma unroll 4
    for (int z = 0; z < 16; z++) {
        const int gz = 2 * (rz * 16 + z);
        long base = (long)gz * D2 + (long)gy * D + gx;
        float2 a00 = *(const float2*)(src + base);
        float2 a01 = *(const float2*)(src + base + D);
        float2 a10 = *(const float2*)(src + base + D2);
        float2 a11 = *(const float2*)(src + base + D2 + D);
        float lo = fminf(fminf(fminf(a00.x, a00.y), fminf(a01.x, a01.y)),
                         fminf(fminf(a10.x, a10.y), fminf(a11.x, a11.y)));
        float hi = fmaxf(fmaxf(fmaxf(a00.x, a00.y), fmaxf(a01.x, a01.y)),
                         fmaxf(fmaxf(a10.x, a10.y), fmaxf(a11.x, a11.y)));
        mnv[0] = fminf(mnv[0], lo); mxv[0] = fmaxf(mxv[0], hi);
        float s = (a00.x + a00.y + a01.x + a01.y +
                   a10.x + a10.y + a11.x + a11.y) * 0.125f;
        mnv[1] = fminf(mnv[1], s); mxv[1] = fmaxf(mxv[1], s);
        d1[(long)(rz * 16 + z) * 96 * 96 + (ry * 16 + ty) * 96 + (rx * 16 + tx)] = s;
        L1[z * 256 + ty * 16 + tx] = s;
    }
    __syncthreads();

#pragma unroll
    for (int k = 0; k < 2; k++) {
        int o = tid + (k << 8);
        int x = o & 7, y = (o >> 3) & 7, z = o >> 6;
        float s = (L1[(2 * z) * 256 + (2 * y) * 16 + 2 * x] +
                   L1[(2 * z) * 256 + (2 * y) * 16 + 2 * x + 1] +
                   L1[(2 * z) * 256 + (2 * y + 1) * 16 + 2 * x] +
                   L1[(2 * z) * 256 + (2 * y + 1) * 16 + 2 * x + 1] +
                   L1[(2 * z + 1) * 256 + (2 * y) * 16 + 2 * x] +
                   L1[(2 * z + 1) * 256 + (2 * y) * 16 + 2 * x + 1] +
                   L1[(2 * z + 1) * 256 + (2 * y + 1) * 16 + 2 * x] +
                   L1[(2 * z + 1) * 256 + (2 * y + 1) * 16 + 2 * x + 1]) * 0.125f;
        mnv[2] = fminf(mnv[2], s); mxv[2] = fmaxf(mxv[2], s);
        d2[(long)(rz * 8 + z) * 48 * 48 + (ry * 8 + y) * 48 + (rx * 8 + x)] = s;
        L2[o] = s;
    }
    __syncthreads();

    if (tid < 64) {
        int x = tid & 3, y = (tid >> 2) & 3, z = tid >> 4;
        float s = (L2[(2 * z) * 64 + (2 * y) * 8 + 2 * x] +
                   L2[(2 * z) * 64 + (2 * y) * 8 + 2 * x + 1] +
                   L2[(2 * z) * 64 + (2 * y + 1) * 8 + 2 * x] +
                   L2[(2 * z) * 64 + (2 * y + 1) * 8 + 2 * x + 1] +
                   L2[(2 * z + 1) * 64 + (2 * y) * 8 + 2 * x] +
                   L2[(2 * z + 1) * 64 + (2 * y) * 8 + 2 * x + 1] +
                   L2[(2 * z + 1) * 64 + (2 * y + 1) * 8 + 2 * x] +
                   L2[(2 * z + 1) * 64 + (2 * y + 1) * 8 + 2 * x + 1]) * 0.125f;
        mnv[3] = fminf(mnv[3], s); mxv[3] = fmaxf(mxv[3], s);
        d3[(long)(rz * 4 + z) * 24 * 24 + (ry * 4 + y) * 24 + (rx * 4 + x)] = s;
        L3[tid] = s;
    }
    __syncthreads();

    if (tid < 8) {
        int x = tid & 1, y = (tid >> 1) & 1, z = tid >> 2;
        float s = (L3[(2 * z) * 16 + (2 * y) * 4 + 2 * x] +
                   L3[(2 * z) * 16 + (2 * y) * 4 + 2 * x + 1] +
                   L3[(2 * z) * 16 + (2 * y + 1) * 4 + 2 * x] +
                   L3[(2 * z) * 16 + (2 * y + 1) * 4 + 2 * x + 1] +
                   L3[(2 * z + 1) * 16 + (2 * y) * 4 + 2 * x] +
                   L3[(2 * z + 1) * 16 + (2 * y) * 4 + 2 * x + 1] +
                   L3[(2 * z + 1) * 16 + (2 * y + 1) * 4 + 2 * x] +
                   L3[(2 * z + 1) * 16 + (2 * y + 1) * 4 + 2 * x + 1]) * 0.125f;
        mnv[4] = fminf(mnv[4], s); mxv[4] = fmaxf(mxv[4], s);
        d4[(long)(rz * 2 + z) * 12 * 12 + (ry * 2 + y) * 12 + (rx * 2 + x)] = s;
    }

    const int lane = tid & 63, w = tid >> 6;
#pragma unroll
    for (int l = 0; l < 5; l++) {
        float mn = mnv[l], mx = mxv[l];
        for (int o = 32; o; o >>= 1) {
            mn = fminf(mn, __shfl_down(mn, o));
            mx = fmaxf(mx, __shfl_down(mx, o));
        }
        __syncthreads();
        if (lane == 0) { smn[w] = mn; smx[w] = mx; }
        __syncthreads();
        if (tid == 0 && im == 0) {
            for (int i = 1; i < 4; i++) { mn = fminf(mn, smn[i]); mx = fmaxf(mx, smx[i]); }
            atomicMin(&wsu[10 + l], enc_f(mn));
            atomicMax(&wsu[15 + l], enc_f(mx));
        }
    }
}

// ---------------------------------------------------------------------------
// Combined SSIM kernel: one dispatch, all 5 levels + fused final reduction.
// 16(x) x 32(y) output tile; thread owns (col, 2 rows). Per plane:
// stage ext 42x26 float2 -> x-conv (4-col runs) -> y-conv (2 rows share 12
// reads) -> systolic z-accumulate A[k]=fma(g[10-k],s,A[k+1]).
// ---------------------------------------------------------------------------
#define TSX 16
#define TSY 32
#define EXR 42            // ext rows (32+10)
#define EXC 26            // ext cols (16+10)
#define SPS 30            // S row stride in float2 (60 floats: odd float4 stride)
#define NPIX (EXR * EXC)  // 1092
#define TPS 17            // TX row stride (float4 / float units)

struct AllParams {
    const float* A[5];
    const float* B[5];
    int D[5], O[5], zc[5], nTx[5], nTy[5];
    int blk0[6];          // cumulative block offsets, level order 0..4
    float* out;
    double cnt[5];
};

__launch_bounds__(256, 2)
__attribute__((amdgpu_waves_per_eu(2, 2)))
__global__ void ssim_all_kernel(AllParams P, float* wsf) {
    __shared__ __align__(16) float2 S[EXR * SPS];    // 10080 B
    __shared__ __align__(16) float4 TX4[EXR * TPS];  // 11424 B
    __shared__ float TXe[EXR * TPS];                 //  2856 B
    __shared__ float2 RED[256];                      //  2048 B

    const int tid = threadIdx.x;
    const int col = tid & 15;
    const int yg  = tid >> 4;      // 0..15, owns output rows 2yg, 2yg+1

    // ---- decode level + tile from flat blockIdx.x
    int level = 0;
    {
        int b = blockIdx.x;
#pragma unroll
        for (int l = 1; l < 5; l++)
            if (b >= P.blk0[l]) level = l;
    }
    int rel = blockIdx.x - P.blk0[level];
    const int D   = P.D[level];
    const int O   = P.O[level];
    const int ZC  = P.zc[level];
    const int nTx = P.nTx[level];
    const int nTy = P.nTy[level];

    const int tx = rel % nTx;  rel /= nTx;
    const int ty = rel % nTy;  rel /= nTy;
    const int batch = rel & 1;
    const int chunk = rel >> 1;

    const int oz0 = chunk * ZC;
    const int oz1 = min(oz0 + ZC, O);
    const int nplanes = oz1 - oz0 + 10;
    const int ox0 = tx * TSX;
    const int oy0 = ty * TSY;
    const int D2  = D * D;
    const float* A = P.A[level] + (long)batch * D * D2;
    const float* B = P.B[level] + (long)batch * D * D2;

    // Gaussian taps (matches np float32: exp(-(i-5)^2/4.5) / sum)
    float g[11];
    {
        float s = 0.f;
#pragma unroll
        for (int i = 0; i < 11; i++) {
            float d = (float)(i - 5);
            g[i] = expf(-d * d / 4.5f);
            s += g[i];
        }
#pragma unroll
        for (int i = 0; i < 11; i++) g[i] /= s;
    }

    // C1/C2 from this level's img1 min/max (computed by pyramid kernel)
    const unsigned* wsu = (const unsigned*)wsf;
    float mxv = dec_f(wsu[15 + level]);
    float mnv = dec_f(wsu[10 + level]);
    float maxval = (mxv > 128.f) ? 255.f : 1.f;
    float minval = (mnv < -0.5f) ? -1.f : 0.f;
    float Lr = maxval - minval;
    float C1 = 0.01f * Lr; C1 *= C1;
    float C2 = 0.03f * Lr; C2 *= C2;

    // per-thread staging slots (plane-invariant offsets); 1092 = 42*26
    int  poff[5], sidx[5];
    bool pval[5];
#pragma unroll
    for (int k = 0; k < 5; k++) {
        int idx = tid + (k << 8);
        pval[k] = (idx < NPIX);
        int row = idx / EXC;
        int c   = idx - row * EXC;
        sidx[k] = row * SPS + c;
        int gy = min(oy0 + row, D - 1);
        int gx = min(ox0 + c,   D - 1);
        poff[k] = gy * D + gx;
    }

    // systolic z accumulators: Acc[f*2+r][k]; out plane completes in [..][0]
    float Acc[10][11] = {};
    float ssim_acc = 0.f, cs_acc = 0.f;

    const bool vx  = (ox0 + col < O);
    const bool vy0 = vx && (oy0 + 2 * yg < O);
    const bool vy1 = vx && (oy0 + 2 * yg + 1 < O);

    // preload first plane
    float2 Pld[5];
    {
        long zoff = (long)oz0 * D2;
#pragma unroll
        for (int k = 0; k < 5; k++)
            if (pval[k]) Pld[k] = make_float2(A[zoff + poff[k]], B[zoff + poff[k]]);
    }

    for (int pc = 0; pc < nplanes; ++pc) {
        __syncthreads();  // prior x-conv S-reads & y-conv TX-reads complete
#pragma unroll
        for (int k = 0; k < 5; k++)
            if (pval[k]) S[sidx[k]] = Pld[k];
        if (pc + 1 < nplanes) {
            long zoff = (long)(oz0 + pc + 1) * D2;
#pragma unroll
            for (int k = 0; k < 5; k++)
                if (pval[k]) Pld[k] = make_float2(A[zoff + poff[k]], B[zoff + poff[k]]);
        }
        __syncthreads();

        // ---- x-conv: 168 tasks, each a run of 4 output cols in one ext row
        if (tid < EXR * 4) {
            int row = tid >> 2;
            int cg  = tid & 3;          // c0 = 4*cg
            const float4* srow = (const float4*)(S + row * SPS);
            float pa[14], pb[14];
#pragma unroll
            for (int i = 0; i < 7; i++) {
                float4 q = srow[2 * cg + i];
                pa[2 * i] = q.x; pb[2 * i] = q.y;
                pa[2 * i + 1] = q.z; pb[2 * i + 1] = q.w;
            }
#pragma unroll
            for (int cc = 0; cc < 4; cc++) {
                float m1 = 0.f, m2 = 0.f, aa = 0.f, bb = 0.f, ab = 0.f;
#pragma unroll
                for (int j = 0; j < 11; j++) {
                    float w = g[j];
                    float a = pa[cc + j], b = pb[cc + j];
                    float wa = w * a, wb = w * b;
                    m1 += wa; m2 += wb;
                    aa += wa * a; bb += wb * b; ab += wa * b;
                }
                int o = row * TPS + 4 * cg + cc;
                TX4[o] = make_float4(m1, m2, aa, bb);
                TXe[o] = ab;
            }
        }
        __syncthreads();

        // ---- y-conv: 2 output rows share 12 row-reads
        float se[5] = {0.f, 0.f, 0.f, 0.f, 0.f};
        float so[5] = {0.f, 0.f, 0.f, 0.f, 0.f};
#pragma unroll
        for (int j = 0; j < 12; j++) {
            int o = (2 * yg + j) * TPS + col;
            float4 q = TX4[o];
            float e  = TXe[o];
            if (j < 11) {
                float w = g[j];
                se[0] += w * q.x; se[1] += w * q.y; se[2] += w * q.z;
                se[3] += w * q.w; se[4] += w * e;
            }
            if (j > 0) {
                float w = g[j - 1];
                so[0] += w * q.x; so[1] += w * q.y; so[2] += w * q.z;
                so[3] += w * q.w; so[4] += w * e;
            }
        }

        // ---- systolic z-accumulate: A[k] = g[10-k]*s + A[k+1]
#pragma unroll
        for (int f = 0; f < 5; f++) {
#pragma unroll
            for (int k = 0; k < 10; k++)
                Acc[2 * f][k] = fmaf(g[10 - k], se[f], Acc[2 * f][k + 1]);
            Acc[2 * f][10] = g[0] * se[f];
#pragma unroll
            for (int k = 0; k < 10; k++)
                Acc[2 * f + 1][k] = fmaf(g[10 - k], so[f], Acc[2 * f + 1][k + 1]);
            Acc[2 * f + 1][10] = g[0] * so[f];
        }

        // ---- completed output plane: Acc[..][0] now holds plane pc-10..pc conv
        if (pc >= 10) {
#pragma unroll
            for (int r = 0; r < 2; r++) {
                bool valid = r ? vy1 : vy0;
                if (!valid) continue;
                float m1  = Acc[0 + r][0], m2  = Acc[2 + r][0];
                float s11 = Acc[4 + r][0], s22 = Acc[6 + r][0], s12 = Acc[8 + r][0];
                float mu11 = m1 * m1, mu22 = m2 * m2, mu12 = m1 * m2;
                float sg1 = s11 - mu11, sg2 = s22 - mu22, sg12 = s12 - mu12;
                float v1 = 2.f * sg12 + C2;
                float v2 = sg1 + sg2 + C2;
                cs_acc   += v1 / v2;
                ssim_acc += ((2.f * mu12 + C1) * v1) / ((mu11 + mu22 + C1) * v2);
            }
        }
    }

    // block reduce + one atomic pair; last block computes the final output
    RED[tid] = make_float2(ssim_acc, cs_acc);
    __syncthreads();
    for (int s = 128; s > 0; s >>= 1) {
        if (tid < s) {
            RED[tid].x += RED[tid + s].x;
            RED[tid].y += RED[tid + s].y;
        }
        __syncthreads();
    }
    if (tid == 0) {
        atomicAdd(&wsf[level],     RED[0].x);
        atomicAdd(&wsf[5 + level], RED[0].y);
        __threadfence();
        unsigned prev = atomicAdd((unsigned*)wsf + 20, 1u);
        if (prev == (unsigned)(P.blk0[5] - 1)) {
            // all blocks' sums are globally visible (their adds precede the
            // counter increment); read via device-scope RMW to dodge stale L2.
            double w[5];
            w[0] = (double)0.0448f; w[1] = (double)0.2856f; w[2] = (double)0.3001f;
            w[3] = (double)0.2363f; w[4] = (double)0.1333f;
            double prod = 1.0;
            for (int l = 0; l < 4; l++) {
                float cs = atomicAdd(&wsf[5 + l], 0.0f);
                prod *= pow((double)cs / P.cnt[l], w[l]);
            }
            float sm = atomicAdd(&wsf[4], 0.0f);
            prod *= pow((double)sm / P.cnt[4], w[4]);
            P.out[0] = (float)prod;
        }
    }
}

extern "C" void kernel_launch(void* const* d_in, const int* in_sizes, int n_in,
                              void* d_out, int out_size, void* d_ws, size_t ws_size,
                              hipStream_t stream) {
    (void)in_sizes; (void)n_in; (void)out_size; (void)ws_size;
    const float* img1 = (const float*)d_in[0];
    const float* img2 = (const float*)d_in[1];
    float* wsf = (float*)d_ws;
    float* out = (float*)d_out;

    const int Ds[5]  = {192, 96, 48, 24, 12};
    // uniform-duration slicing: L0 26*7=182 exact (36-plane blocks); tail
    // levels sliced <=26 planes so they pack into scheduler gaps.
    const int ZCs[5] = {26, 16, 14, 14, 2};

    // pyramid buffers in workspace
    float* bufA[5] = {nullptr};
    float* bufB[5] = {nullptr};
    size_t o = 32;
    for (int l = 1; l < 5; l++) {
        long n = 2L * Ds[l] * Ds[l] * Ds[l];
        bufA[l] = wsf + o; o += (size_t)n;
        bufB[l] = wsf + o; o += (size_t)n;
    }

    init_kernel<<<1, 64, 0, stream>>>(wsf);

    PyrParams PP;
    PP.src[0] = img1; PP.src[1] = img2;
    for (int l = 1; l < 5; l++) { PP.dst[0][l - 1] = bufA[l]; PP.dst[1][l - 1] = bufB[l]; }
    pyramid_kernel<<<216 * 2 * 2, 256, 0, stream>>>(PP, wsf);

    AllParams P;
    P.A[0] = img1; P.B[0] = img2;
    for (int l = 1; l < 5; l++) { P.A[l] = bufA[l]; P.B[l] = bufB[l]; }
    P.out = out;
    int acc = 0;
    for (int l = 0; l < 5; l++) {
        int D = Ds[l], O = D - 10, ZC = ZCs[l];
        int nTx = (O + TSX - 1) / TSX;
        int nTy = (O + TSY - 1) / TSY;
        int ZCn = (O + ZC - 1) / ZC;
        P.D[l] = D; P.O[l] = O; P.zc[l] = ZC; P.nTx[l] = nTx; P.nTy[l] = nTy;
        P.blk0[l] = acc;
        acc += nTx * nTy * 2 * ZCn;
        double Od = (double)O;
        P.cnt[l] = 2.0 * Od * Od * Od;
    }
    P.blk0[5] = acc;
    ssim_all_kernel<<<acc, 256, 0, stream>>>(P, wsf);
}